// Round 1
// baseline (656.366 us; speedup 1.0000x reference)
//
#include <hip/hip_runtime.h>

#define NU 120000
#define NI 80000
#define NN 200000
#define DD 64
#define NE 1280000
#define BB 4096
#define NS 8192  // 2*B sampled nodes

// ---------------- CSR build ----------------
__global__ void k_hist(const int* __restrict__ dst, int* __restrict__ counts) {
  int e = blockIdx.x * blockDim.x + threadIdx.x;
  if (e < NE) atomicAdd(&counts[dst[e]], 1);
}

__global__ void k_scan_blocks(const int* __restrict__ counts, int* __restrict__ row_ptr,
                              int* __restrict__ bsums) {
  __shared__ int s[256];
  int i = blockIdx.x * 256 + threadIdx.x;
  int x = (i < NN) ? counts[i] : 0;
  s[threadIdx.x] = x;
  __syncthreads();
  for (int off = 1; off < 256; off <<= 1) {
    int t = (threadIdx.x >= off) ? s[threadIdx.x - off] : 0;
    __syncthreads();
    s[threadIdx.x] += t;
    __syncthreads();
  }
  if (i < NN) row_ptr[i] = s[threadIdx.x] - x;  // exclusive
  if (threadIdx.x == 255) bsums[blockIdx.x] = s[255];
}

__global__ void k_scan_top(int* __restrict__ bsums, int nblk) {
  __shared__ int s[1024];
  int x = (threadIdx.x < nblk) ? bsums[threadIdx.x] : 0;
  s[threadIdx.x] = x;
  __syncthreads();
  for (int off = 1; off < 1024; off <<= 1) {
    int t = (threadIdx.x >= off) ? s[threadIdx.x - off] : 0;
    __syncthreads();
    s[threadIdx.x] += t;
    __syncthreads();
  }
  if (threadIdx.x < nblk) bsums[threadIdx.x] = s[threadIdx.x] - x;  // exclusive
}

__global__ void k_add_off(int* __restrict__ row_ptr, const int* __restrict__ bsums) {
  int i = blockIdx.x * 256 + threadIdx.x;
  if (i < NN) row_ptr[i] += bsums[blockIdx.x];
  if (i == 0) row_ptr[NN] = NE;
}

__global__ void k_scatter(const int* __restrict__ src, const int* __restrict__ dst,
                          const float* __restrict__ val, const int* __restrict__ row_ptr,
                          int* __restrict__ cursor, int* __restrict__ csr_src,
                          float* __restrict__ csr_val) {
  int e = blockIdx.x * blockDim.x + threadIdx.x;
  if (e >= NE) return;
  int d = dst[e];
  int pos = row_ptr[d] + atomicAdd(&cursor[d], 1);
  csr_src[pos] = src[e];
  csr_val[pos] = val[e];
}

// ---------------- propagation: one wave per node, lane = dim ----------------
__global__ void k_prop(const float* __restrict__ Ein, float* __restrict__ Eout,
                       const int* __restrict__ row_ptr, const int* __restrict__ csr_src,
                       const float* __restrict__ csr_val) {
  int wid = (blockIdx.x * blockDim.x + threadIdx.x) >> 6;
  int lane = threadIdx.x & 63;
  if (wid >= NN) return;
  int start = row_ptr[wid], end = row_ptr[wid + 1];
  float acc = 0.f;
  for (int j = start; j < end; ++j) {
    int s = csr_src[j];
    float v = csr_val[j];
    acc += v * Ein[(size_t)s * DD + lane];
  }
  Eout[(size_t)wid * DD + lane] = acc;
}

// gather sampled nodes for one layer into Es[l] (NS x 64)
__global__ void k_gather(const float* __restrict__ E, float* __restrict__ Es_l,
                         const int* __restrict__ u, const int* __restrict__ ii) {
  int t = blockIdx.x * blockDim.x + threadIdx.x;
  if (t >= NS * 16) return;
  int p = t >> 4, q = t & 15;
  int node = (p < BB) ? u[p] : NU + ii[p - BB];
  reinterpret_cast<float4*>(Es_l)[p * 16 + q] =
      reinterpret_cast<const float4*>(E)[(size_t)node * 16 + q];
}

// ---------------- attention + scoring: one wave per pair ----------------
__global__ void k_attn(const float* __restrict__ Es,  // (4, NS, 64)
                       const float* __restrict__ Wq, const float* __restrict__ Wk,
                       const float* __restrict__ Wv, const float* __restrict__ Wo,
                       float* __restrict__ out) {
  int w = (blockIdx.x * blockDim.x + threadIdx.x) >> 6;
  int lane = threadIdx.x & 63;
  if (w >= BB) return;
  const float inv_scale = 0.17677669529663687f;  // 1/sqrt(32)
  float eo[2];
  for (int side = 0; side < 2; ++side) {
    int p = side ? (BB + w) : w;
    float e0 = Es[(size_t)0 * NS * DD + p * DD + lane];
    float e1 = Es[(size_t)1 * NS * DD + p * DD + lane];
    float e2 = Es[(size_t)2 * NS * DD + p * DD + lane];
    float e3 = Es[(size_t)3 * NS * DD + p * DD + lane];

    // Q[h,k] for output j=lane (h=j>>5, k=j&31):  Q = e0 @ Wq(64x64 flat)
    float q = 0.f;
    for (int d = 0; d < 64; ++d) q += __shfl(e0, d) * Wq[d * 64 + lane];

    // t_h[d=lane] = sum_k Wk[lane,h,k] * Q[h,k]
    float t0 = 0.f, t1 = 0.f;
    for (int k = 0; k < 32; ++k) {
      t0 += Wk[lane * 64 + k] * __shfl(q, k);
      t1 += Wk[lane * 64 + 32 + k] * __shfl(q, 32 + k);
    }

    // scores[l,h] = (Es[l] . t_h) / sqrt(dk)
    float el[4] = {e0, e1, e2, e3};
    float sc[4][2];
#pragma unroll
    for (int l = 0; l < 4; ++l) {
      float p0 = el[l] * t0, p1 = el[l] * t1;
#pragma unroll
      for (int o = 32; o; o >>= 1) {
        p0 += __shfl_xor(p0, o);
        p1 += __shfl_xor(p1, o);
      }
      sc[l][0] = p0 * inv_scale;
      sc[l][1] = p1 * inv_scale;
    }

    // softmax over l, per head; Ebar_h = sum_l alpha[l,h] * e_l
    float eb[2];
#pragma unroll
    for (int h = 0; h < 2; ++h) {
      float m = fmaxf(fmaxf(sc[0][h], sc[1][h]), fmaxf(sc[2][h], sc[3][h]));
      float ex0 = expf(sc[0][h] - m), ex1 = expf(sc[1][h] - m);
      float ex2 = expf(sc[2][h] - m), ex3 = expf(sc[3][h] - m);
      float inv = 1.f / (ex0 + ex1 + ex2 + ex3);
      eb[h] = (ex0 * e0 + ex1 * e1 + ex2 * e2 + ex3 * e3) * inv;
    }

    // heads[h,v] for output j=lane: sum_d Ebar[h][d] * Wv[d,h,v]  (flat d*64 + lane)
    int h = lane >> 5;
    float hd = 0.f;
    for (int d = 0; d < 64; ++d) {
      float v0 = __shfl(eb[0], d), v1 = __shfl(eb[1], d);
      hd += (h ? v1 : v0) * Wv[d * 64 + lane];
    }

    // E_out[d=lane] = sum_m heads[m] * Wo[m, lane]
    float e_ = 0.f;
    for (int m = 0; m < 64; ++m) e_ += __shfl(hd, m) * Wo[m * 64 + lane];
    eo[side] = e_;
  }
  float pd = eo[0] * eo[1];
#pragma unroll
  for (int o = 32; o; o >>= 1) pd += __shfl_xor(pd, o);
  if (lane == 0) out[w] = pd;
}

extern "C" void kernel_launch(void* const* d_in, const int* in_sizes, int n_in,
                              void* d_out, int out_size, void* d_ws, size_t ws_size,
                              hipStream_t stream) {
  const int* edge_src = (const int*)d_in[0];
  const int* edge_dst = (const int*)d_in[1];
  const float* edge_val = (const float*)d_in[2];
  const float* U_emb = (const float*)d_in[3];
  const float* V_emb = (const float*)d_in[4];
  const float* Wq = (const float*)d_in[5];
  const float* Wk = (const float*)d_in[6];
  const float* Wv = (const float*)d_in[7];
  const float* Wo = (const float*)d_in[8];
  const int* u = (const int*)d_in[9];
  const int* ii = (const int*)d_in[10];
  float* out = (float*)d_out;

  // workspace layout
  float* Ea = (float*)d_ws;                      // NN*64
  float* Eb = Ea + (size_t)NN * DD;              // NN*64
  float* Es = Eb + (size_t)NN * DD;              // 4*NS*64
  int* row_ptr = (int*)(Es + (size_t)4 * NS * DD);  // NN+1
  int* cursor = row_ptr + NN + 1;                // NN
  int* bsums = cursor + NN;                      // 1024
  int* csr_src = bsums + 1024;                   // NE
  float* csr_val = (float*)(csr_src + NE);       // NE

  // E0 = concat(U_emb, V_emb)
  hipMemcpyAsync(Ea, U_emb, (size_t)NU * DD * sizeof(float), hipMemcpyDeviceToDevice, stream);
  hipMemcpyAsync(Ea + (size_t)NU * DD, V_emb, (size_t)NI * DD * sizeof(float),
                 hipMemcpyDeviceToDevice, stream);

  // CSR build (counts use `cursor` storage)
  hipMemsetAsync(cursor, 0, NN * sizeof(int), stream);
  k_hist<<<(NE + 255) / 256, 256, 0, stream>>>(edge_dst, cursor);
  int nblk = (NN + 255) / 256;  // 782
  k_scan_blocks<<<nblk, 256, 0, stream>>>(cursor, row_ptr, bsums);
  k_scan_top<<<1, 1024, 0, stream>>>(bsums, nblk);
  k_add_off<<<nblk, 256, 0, stream>>>(row_ptr, bsums);
  hipMemsetAsync(cursor, 0, NN * sizeof(int), stream);
  k_scatter<<<(NE + 255) / 256, 256, 0, stream>>>(edge_src, edge_dst, edge_val, row_ptr, cursor,
                                                  csr_src, csr_val);

  int ggrid = (NS * 16 + 255) / 256;
  int pgrid = (NN * DD + 255) / 256;

  k_gather<<<ggrid, 256, 0, stream>>>(Ea, Es + (size_t)0 * NS * DD, u, ii);  // E0 sample
  k_prop<<<pgrid, 256, 0, stream>>>(Ea, Eb, row_ptr, csr_src, csr_val);      // E1
  k_gather<<<ggrid, 256, 0, stream>>>(Eb, Es + (size_t)1 * NS * DD, u, ii);
  k_prop<<<pgrid, 256, 0, stream>>>(Eb, Ea, row_ptr, csr_src, csr_val);      // E2
  k_gather<<<ggrid, 256, 0, stream>>>(Ea, Es + (size_t)2 * NS * DD, u, ii);
  k_prop<<<pgrid, 256, 0, stream>>>(Ea, Eb, row_ptr, csr_src, csr_val);      // E3
  k_gather<<<ggrid, 256, 0, stream>>>(Eb, Es + (size_t)3 * NS * DD, u, ii);

  k_attn<<<(BB * 64 + 255) / 256, 256, 0, stream>>>(Es, Wq, Wk, Wv, Wo, out);
}

// Round 2
// 370.539 us; speedup vs baseline: 1.7714x; 1.7714x over previous
//
#include <hip/hip_runtime.h>

#define NU 120000
#define NI 80000
#define NN 200000
#define DD 64
#define NE 1280000
#define BB 4096
#define NS 8192  // 2*B sampled nodes

// ---------------- CSR build ----------------
__global__ void k_hist(const int* __restrict__ dst, int* __restrict__ counts) {
  int e = blockIdx.x * blockDim.x + threadIdx.x;
  if (e < NE) atomicAdd(&counts[dst[e]], 1);
}

__global__ void k_scan_blocks(const int* __restrict__ counts, int* __restrict__ row_ptr,
                              int* __restrict__ bsums) {
  __shared__ int s[256];
  int i = blockIdx.x * 256 + threadIdx.x;
  int x = (i < NN) ? counts[i] : 0;
  s[threadIdx.x] = x;
  __syncthreads();
  for (int off = 1; off < 256; off <<= 1) {
    int t = (threadIdx.x >= off) ? s[threadIdx.x - off] : 0;
    __syncthreads();
    s[threadIdx.x] += t;
    __syncthreads();
  }
  if (i < NN) row_ptr[i] = s[threadIdx.x] - x;  // exclusive
  if (threadIdx.x == 255) bsums[blockIdx.x] = s[255];
}

__global__ void k_scan_top(int* __restrict__ bsums, int nblk) {
  __shared__ int s[1024];
  int x = (threadIdx.x < nblk) ? bsums[threadIdx.x] : 0;
  s[threadIdx.x] = x;
  __syncthreads();
  for (int off = 1; off < 1024; off <<= 1) {
    int t = (threadIdx.x >= off) ? s[threadIdx.x - off] : 0;
    __syncthreads();
    s[threadIdx.x] += t;
    __syncthreads();
  }
  if (threadIdx.x < nblk) bsums[threadIdx.x] = s[threadIdx.x] - x;  // exclusive
}

__global__ void k_add_off(int* __restrict__ row_ptr, const int* __restrict__ bsums) {
  int i = blockIdx.x * 256 + threadIdx.x;
  if (i < NN) row_ptr[i] += bsums[blockIdx.x];
  if (i == 0) row_ptr[NN] = NE;
}

__global__ void k_scatter(const int* __restrict__ src, const int* __restrict__ dst,
                          const float* __restrict__ val, const int* __restrict__ row_ptr,
                          int* __restrict__ cursor, int2* __restrict__ pairs) {
  int e = blockIdx.x * blockDim.x + threadIdx.x;
  if (e >= NE) return;
  int d = dst[e];
  int pos = row_ptr[d] + atomicAdd(&cursor[d], 1);
  pairs[pos] = make_int2(src[e], __float_as_int(val[e]));
}

// ---------------- frontier marking ----------------
// need2 = S ∪ in-nbrs(S);  need1 = S ∪ in-nbrs(need2)
__global__ void k_mark_s(const int* __restrict__ u, const int* __restrict__ ii,
                         const int* __restrict__ row_ptr, const int2* __restrict__ pairs,
                         int* __restrict__ need1, int* __restrict__ need2) {
  int t = blockIdx.x * blockDim.x + threadIdx.x;
  if (t >= NS) return;
  int node = (t < BB) ? u[t] : NU + ii[t - BB];
  need2[node] = 1;
  need1[node] = 1;
  int s = row_ptr[node], e = row_ptr[node + 1];
  for (int j = s; j < e; ++j) need2[pairs[j].x] = 1;
}

__global__ void k_mark2(const int* __restrict__ row_ptr, const int2* __restrict__ pairs,
                        const int* __restrict__ need2, int* __restrict__ need1) {
  int n = blockIdx.x * blockDim.x + threadIdx.x;
  if (n >= NN || !need2[n]) return;
  int s = row_ptr[n], e = row_ptr[n + 1];
  for (int j = s; j < e; ++j) need1[pairs[j].x] = 1;
}

// ---------------- propagation: one wave per node, 4 edges x 16 dim-chunks ----------------
// lane: sub = lane>>4 (edge slot 0..3), c = lane&15 (float4 chunk)
template <int L0>
__global__ void k_prop4(const float4* __restrict__ U4, const float4* __restrict__ V4,
                        const float4* __restrict__ E4in, float4* __restrict__ E4out,
                        const int* __restrict__ row_ptr, const int2* __restrict__ pairs,
                        const int* __restrict__ need) {
  int wid = (blockIdx.x * blockDim.x + threadIdx.x) >> 6;
  if (wid >= NN) return;
  if (!need[wid]) return;
  int lane = threadIdx.x & 63;
  int sub = lane >> 4, c = lane & 15;
  int start = row_ptr[wid], end = row_ptr[wid + 1];
  float4 acc = make_float4(0.f, 0.f, 0.f, 0.f);
  for (int j0 = start; j0 < end; j0 += 4) {
    int j = j0 + sub;
    bool ok = j < end;
    int jj = ok ? j : start;
    int2 pv = pairs[jj];
    float v = ok ? __int_as_float(pv.y) : 0.f;
    int s = pv.x;
    const float4* base;
    if (L0) {
      base = (s < NU) ? (U4 + (size_t)s * 16) : (V4 + (size_t)(s - NU) * 16);
    } else {
      base = E4in + (size_t)s * 16;
    }
    float4 r = base[c];
    acc.x += v * r.x;
    acc.y += v * r.y;
    acc.z += v * r.z;
    acc.w += v * r.w;
  }
#pragma unroll
  for (int off = 16; off <= 32; off <<= 1) {
    acc.x += __shfl_xor(acc.x, off);
    acc.y += __shfl_xor(acc.y, off);
    acc.z += __shfl_xor(acc.z, off);
    acc.w += __shfl_xor(acc.w, off);
  }
  if (sub == 0) E4out[(size_t)wid * 16 + c] = acc;
}

// prop layer 3: only the 8192 sampled nodes, writes Es[3] directly
__global__ void k_prop3(const float4* __restrict__ E4in, float4* __restrict__ Es3,
                        const int* __restrict__ row_ptr, const int2* __restrict__ pairs,
                        const int* __restrict__ u, const int* __restrict__ ii) {
  int wid = (blockIdx.x * blockDim.x + threadIdx.x) >> 6;
  if (wid >= NS) return;
  int node = (wid < BB) ? u[wid] : NU + ii[wid - BB];
  int lane = threadIdx.x & 63;
  int sub = lane >> 4, c = lane & 15;
  int start = row_ptr[node], end = row_ptr[node + 1];
  float4 acc = make_float4(0.f, 0.f, 0.f, 0.f);
  for (int j0 = start; j0 < end; j0 += 4) {
    int j = j0 + sub;
    bool ok = j < end;
    int jj = ok ? j : start;
    int2 pv = pairs[jj];
    float v = ok ? __int_as_float(pv.y) : 0.f;
    float4 r = E4in[(size_t)pv.x * 16 + c];
    acc.x += v * r.x;
    acc.y += v * r.y;
    acc.z += v * r.z;
    acc.w += v * r.w;
  }
#pragma unroll
  for (int off = 16; off <= 32; off <<= 1) {
    acc.x += __shfl_xor(acc.x, off);
    acc.y += __shfl_xor(acc.y, off);
    acc.z += __shfl_xor(acc.z, off);
    acc.w += __shfl_xor(acc.w, off);
  }
  if (sub == 0) Es3[(size_t)wid * 16 + c] = acc;
}

// gather sampled nodes for one layer into Es[l] (NS x 64). L0: virtual concat of U/V.
template <int L0>
__global__ void k_gather(const float4* __restrict__ U4, const float4* __restrict__ V4,
                         const float4* __restrict__ E4, float4* __restrict__ Es_l,
                         const int* __restrict__ u, const int* __restrict__ ii) {
  int t = blockIdx.x * blockDim.x + threadIdx.x;
  if (t >= NS * 16) return;
  int p = t >> 4, q = t & 15;
  int node = (p < BB) ? u[p] : NU + ii[p - BB];
  float4 r;
  if (L0) {
    r = (node < NU) ? U4[(size_t)node * 16 + q] : V4[(size_t)(node - NU) * 16 + q];
  } else {
    r = E4[(size_t)node * 16 + q];
  }
  Es_l[p * 16 + q] = r;
}

// ---------------- attention + scoring: one wave per pair ----------------
__global__ void k_attn(const float* __restrict__ Es,  // (4, NS, 64)
                       const float* __restrict__ Wq, const float* __restrict__ Wk,
                       const float* __restrict__ Wv, const float* __restrict__ Wo,
                       float* __restrict__ out) {
  int w = (blockIdx.x * blockDim.x + threadIdx.x) >> 6;
  int lane = threadIdx.x & 63;
  if (w >= BB) return;
  const float inv_scale = 0.17677669529663687f;  // 1/sqrt(32)
  float eo[2];
  for (int side = 0; side < 2; ++side) {
    int p = side ? (BB + w) : w;
    float e0 = Es[(size_t)0 * NS * DD + p * DD + lane];
    float e1 = Es[(size_t)1 * NS * DD + p * DD + lane];
    float e2 = Es[(size_t)2 * NS * DD + p * DD + lane];
    float e3 = Es[(size_t)3 * NS * DD + p * DD + lane];

    // Q[h,k] for output j=lane: Q = e0 @ Wq (64x64 flat)
    float q = 0.f;
    for (int d = 0; d < 64; ++d) q += __shfl(e0, d) * Wq[d * 64 + lane];

    // t_h[d=lane] = sum_k Wk[lane,h,k] * Q[h,k]
    float t0 = 0.f, t1 = 0.f;
    for (int k = 0; k < 32; ++k) {
      t0 += Wk[lane * 64 + k] * __shfl(q, k);
      t1 += Wk[lane * 64 + 32 + k] * __shfl(q, 32 + k);
    }

    // scores[l,h] = (Es[l] . t_h) / sqrt(dk)
    float el[4] = {e0, e1, e2, e3};
    float sc[4][2];
#pragma unroll
    for (int l = 0; l < 4; ++l) {
      float p0 = el[l] * t0, p1 = el[l] * t1;
#pragma unroll
      for (int o = 32; o; o >>= 1) {
        p0 += __shfl_xor(p0, o);
        p1 += __shfl_xor(p1, o);
      }
      sc[l][0] = p0 * inv_scale;
      sc[l][1] = p1 * inv_scale;
    }

    // softmax over l, per head; Ebar_h = sum_l alpha[l,h] * e_l
    float eb[2];
#pragma unroll
    for (int h = 0; h < 2; ++h) {
      float m = fmaxf(fmaxf(sc[0][h], sc[1][h]), fmaxf(sc[2][h], sc[3][h]));
      float ex0 = expf(sc[0][h] - m), ex1 = expf(sc[1][h] - m);
      float ex2 = expf(sc[2][h] - m), ex3 = expf(sc[3][h] - m);
      float inv = 1.f / (ex0 + ex1 + ex2 + ex3);
      eb[h] = (ex0 * e0 + ex1 * e1 + ex2 * e2 + ex3 * e3) * inv;
    }

    // heads[h,v] for output j=lane
    int h = lane >> 5;
    float hd = 0.f;
    for (int d = 0; d < 64; ++d) {
      float v0 = __shfl(eb[0], d), v1 = __shfl(eb[1], d);
      hd += (h ? v1 : v0) * Wv[d * 64 + lane];
    }

    // E_out[d=lane] = sum_m heads[m] * Wo[m, lane]
    float e_ = 0.f;
    for (int m = 0; m < 64; ++m) e_ += __shfl(hd, m) * Wo[m * 64 + lane];
    eo[side] = e_;
  }
  float pd = eo[0] * eo[1];
#pragma unroll
  for (int o = 32; o; o >>= 1) pd += __shfl_xor(pd, o);
  if (lane == 0) out[w] = pd;
}

extern "C" void kernel_launch(void* const* d_in, const int* in_sizes, int n_in,
                              void* d_out, int out_size, void* d_ws, size_t ws_size,
                              hipStream_t stream) {
  const int* edge_src = (const int*)d_in[0];
  const int* edge_dst = (const int*)d_in[1];
  const float* edge_val = (const float*)d_in[2];
  const float* U_emb = (const float*)d_in[3];
  const float* V_emb = (const float*)d_in[4];
  const float* Wq = (const float*)d_in[5];
  const float* Wk = (const float*)d_in[6];
  const float* Wv = (const float*)d_in[7];
  const float* Wo = (const float*)d_in[8];
  const int* u = (const int*)d_in[9];
  const int* ii = (const int*)d_in[10];
  float* out = (float*)d_out;

  const float4* U4 = (const float4*)U_emb;
  const float4* V4 = (const float4*)V_emb;

  // workspace layout (16B-aligned base)
  float* Ea = (float*)d_ws;                          // NN*64  (E1)
  float* Eb = Ea + (size_t)NN * DD;                  // NN*64  (E2)
  float* Es = Eb + (size_t)NN * DD;                  // 4*NS*64
  int* row_ptr = (int*)(Es + (size_t)4 * NS * DD);   // NN+1
  int* cursor = row_ptr + NN + 1;                    // NN
  int* bsums = cursor + NN;                          // 1024
  int* need1 = bsums + 1024;                         // NN
  int* need2 = need1 + NN;                           // NN
  // align pairs to 16B
  uintptr_t pa = (uintptr_t)(need2 + NN);
  pa = (pa + 15) & ~(uintptr_t)15;
  int2* pairs = (int2*)pa;                           // NE int2

  float4* Ea4 = (float4*)Ea;
  float4* Eb4 = (float4*)Eb;
  float4* Es4 = (float4*)Es;

  // CSR build (counts use `cursor` storage)
  hipMemsetAsync(cursor, 0, NN * sizeof(int), stream);
  hipMemsetAsync(need1, 0, 2 * NN * sizeof(int), stream);
  k_hist<<<(NE + 255) / 256, 256, 0, stream>>>(edge_dst, cursor);
  int nblk = (NN + 255) / 256;  // 782
  k_scan_blocks<<<nblk, 256, 0, stream>>>(cursor, row_ptr, bsums);
  k_scan_top<<<1, 1024, 0, stream>>>(bsums, nblk);
  k_add_off<<<nblk, 256, 0, stream>>>(row_ptr, bsums);
  hipMemsetAsync(cursor, 0, NN * sizeof(int), stream);
  k_scatter<<<(NE + 255) / 256, 256, 0, stream>>>(edge_src, edge_dst, edge_val, row_ptr, cursor,
                                                  pairs);

  // frontier marking
  k_mark_s<<<(NS + 255) / 256, 256, 0, stream>>>(u, ii, row_ptr, pairs, need1, need2);
  k_mark2<<<nblk, 256, 0, stream>>>(row_ptr, pairs, need2, need1);

  int ggrid = (NS * 16 + 255) / 256;
  int pgrid = (NN * 64 + 255) / 256;

  // layer-0 sample (virtual concat)
  k_gather<1><<<ggrid, 256, 0, stream>>>(U4, V4, nullptr, Es4 + (size_t)0 * NS * 16, u, ii);
  // E1 = A @ E0 (restricted to need1)
  k_prop4<1><<<pgrid, 256, 0, stream>>>(U4, V4, nullptr, Ea4, row_ptr, pairs, need1);
  k_gather<0><<<ggrid, 256, 0, stream>>>(nullptr, nullptr, Ea4, Es4 + (size_t)1 * NS * 16, u, ii);
  // E2 = A @ E1 (restricted to need2)
  k_prop4<0><<<pgrid, 256, 0, stream>>>(nullptr, nullptr, Ea4, Eb4, row_ptr, pairs, need2);
  k_gather<0><<<ggrid, 256, 0, stream>>>(nullptr, nullptr, Eb4, Es4 + (size_t)2 * NS * 16, u, ii);
  // E3 at sampled nodes only, straight into Es[3]
  k_prop3<<<(NS * 64 + 255) / 256, 256, 0, stream>>>(Eb4, Es4 + (size_t)3 * NS * 16, row_ptr,
                                                     pairs, u, ii);

  k_attn<<<(BB * 64 + 255) / 256, 256, 0, stream>>>(Es, Wq, Wk, Wv, Wo, out);
}

// Round 3
// 308.827 us; speedup vs baseline: 2.1253x; 1.1998x over previous
//
#include <hip/hip_runtime.h>

#define NU 120000
#define NI 80000
#define NN 200000
#define DD 64
#define NE 1280000
#define BB 4096
#define NS 8192  // 2*B sampled nodes

// ---------------- CSR build ----------------
__global__ void k_hist(const int* __restrict__ dst, int* __restrict__ counts) {
  int e = blockIdx.x * blockDim.x + threadIdx.x;
  if (e < NE) atomicAdd(&counts[dst[e]], 1);
}

__global__ void k_scan_blocks(const int* __restrict__ counts, int* __restrict__ row_ptr,
                              int* __restrict__ bsums) {
  __shared__ int s[256];
  int i = blockIdx.x * 256 + threadIdx.x;
  int x = (i < NN) ? counts[i] : 0;
  s[threadIdx.x] = x;
  __syncthreads();
  for (int off = 1; off < 256; off <<= 1) {
    int t = (threadIdx.x >= off) ? s[threadIdx.x - off] : 0;
    __syncthreads();
    s[threadIdx.x] += t;
    __syncthreads();
  }
  if (i < NN) row_ptr[i] = s[threadIdx.x] - x;  // exclusive
  if (threadIdx.x == 255) bsums[blockIdx.x] = s[255];
}

__global__ void k_scan_top(int* __restrict__ bsums, int nblk) {
  __shared__ int s[1024];
  int x = (threadIdx.x < nblk) ? bsums[threadIdx.x] : 0;
  s[threadIdx.x] = x;
  __syncthreads();
  for (int off = 1; off < 1024; off <<= 1) {
    int t = (threadIdx.x >= off) ? s[threadIdx.x - off] : 0;
    __syncthreads();
    s[threadIdx.x] += t;
    __syncthreads();
  }
  if (threadIdx.x < nblk) bsums[threadIdx.x] = s[threadIdx.x] - x;  // exclusive
}

__global__ void k_add_off(int* __restrict__ row_ptr, const int* __restrict__ bsums) {
  int i = blockIdx.x * 256 + threadIdx.x;
  if (i < NN) row_ptr[i] += bsums[blockIdx.x];
  if (i == 0) row_ptr[NN] = NE;
}

__global__ void k_scatter(const int* __restrict__ src, const int* __restrict__ dst,
                          const float* __restrict__ val, const int* __restrict__ row_ptr,
                          int* __restrict__ cursor, int2* __restrict__ pairs) {
  int e = blockIdx.x * blockDim.x + threadIdx.x;
  if (e >= NE) return;
  int d = dst[e];
  int pos = row_ptr[d] + atomicAdd(&cursor[d], 1);
  pairs[pos] = make_int2(src[e], __float_as_int(val[e]));
}

// ---------------- frontier marking ----------------
__global__ void k_mark_s(const int* __restrict__ u, const int* __restrict__ ii,
                         const int* __restrict__ row_ptr, const int2* __restrict__ pairs,
                         int* __restrict__ need1, int* __restrict__ need2) {
  int t = blockIdx.x * blockDim.x + threadIdx.x;
  if (t >= NS) return;
  int node = (t < BB) ? u[t] : NU + ii[t - BB];
  need2[node] = 1;
  need1[node] = 1;
  int s = row_ptr[node], e = row_ptr[node + 1];
  for (int j = s; j < e; ++j) need2[pairs[j].x] = 1;
}

__global__ void k_mark2(const int* __restrict__ row_ptr, const int2* __restrict__ pairs,
                        const int* __restrict__ need2, int* __restrict__ need1) {
  int n = blockIdx.x * blockDim.x + threadIdx.x;
  if (n >= NN || !need2[n]) return;
  int s = row_ptr[n], e = row_ptr[n + 1];
  for (int j = s; j < e; ++j) need1[pairs[j].x] = 1;
}

// ---------------- propagation: one wave per node, 4 edges x 16 dim-chunks ----------------
template <int L0>
__global__ void k_prop4(const float4* __restrict__ U4, const float4* __restrict__ V4,
                        const float4* __restrict__ E4in, float4* __restrict__ E4out,
                        const int* __restrict__ row_ptr, const int2* __restrict__ pairs,
                        const int* __restrict__ need) {
  int wid = (blockIdx.x * blockDim.x + threadIdx.x) >> 6;
  if (wid >= NN) return;
  if (!need[wid]) return;
  int lane = threadIdx.x & 63;
  int sub = lane >> 4, c = lane & 15;
  int start = row_ptr[wid], end = row_ptr[wid + 1];
  float4 acc = make_float4(0.f, 0.f, 0.f, 0.f);
  for (int j0 = start; j0 < end; j0 += 4) {
    int j = j0 + sub;
    bool ok = j < end;
    int jj = ok ? j : start;
    int2 pv = pairs[jj];
    float v = ok ? __int_as_float(pv.y) : 0.f;
    int s = pv.x;
    const float4* base;
    if (L0) {
      base = (s < NU) ? (U4 + (size_t)s * 16) : (V4 + (size_t)(s - NU) * 16);
    } else {
      base = E4in + (size_t)s * 16;
    }
    float4 r = base[c];
    acc.x += v * r.x;
    acc.y += v * r.y;
    acc.z += v * r.z;
    acc.w += v * r.w;
  }
#pragma unroll
  for (int off = 16; off <= 32; off <<= 1) {
    acc.x += __shfl_xor(acc.x, off);
    acc.y += __shfl_xor(acc.y, off);
    acc.z += __shfl_xor(acc.z, off);
    acc.w += __shfl_xor(acc.w, off);
  }
  if (sub == 0) E4out[(size_t)wid * 16 + c] = acc;
}

// prop layer 3: only the 8192 sampled nodes, writes Es[3] directly
__global__ void k_prop3(const float4* __restrict__ E4in, float4* __restrict__ Es3,
                        const int* __restrict__ row_ptr, const int2* __restrict__ pairs,
                        const int* __restrict__ u, const int* __restrict__ ii) {
  int wid = (blockIdx.x * blockDim.x + threadIdx.x) >> 6;
  if (wid >= NS) return;
  int node = (wid < BB) ? u[wid] : NU + ii[wid - BB];
  int lane = threadIdx.x & 63;
  int sub = lane >> 4, c = lane & 15;
  int start = row_ptr[node], end = row_ptr[node + 1];
  float4 acc = make_float4(0.f, 0.f, 0.f, 0.f);
  for (int j0 = start; j0 < end; j0 += 4) {
    int j = j0 + sub;
    bool ok = j < end;
    int jj = ok ? j : start;
    int2 pv = pairs[jj];
    float v = ok ? __int_as_float(pv.y) : 0.f;
    float4 r = E4in[(size_t)pv.x * 16 + c];
    acc.x += v * r.x;
    acc.y += v * r.y;
    acc.z += v * r.z;
    acc.w += v * r.w;
  }
#pragma unroll
  for (int off = 16; off <= 32; off <<= 1) {
    acc.x += __shfl_xor(acc.x, off);
    acc.y += __shfl_xor(acc.y, off);
    acc.z += __shfl_xor(acc.z, off);
    acc.w += __shfl_xor(acc.w, off);
  }
  if (sub == 0) Es3[(size_t)wid * 16 + c] = acc;
}

// gather sampled nodes for one layer into Es[l] (NS x 64). L0: virtual concat of U/V.
template <int L0>
__global__ void k_gather(const float4* __restrict__ U4, const float4* __restrict__ V4,
                         const float4* __restrict__ E4, float4* __restrict__ Es_l,
                         const int* __restrict__ u, const int* __restrict__ ii) {
  int t = blockIdx.x * blockDim.x + threadIdx.x;
  if (t >= NS * 16) return;
  int p = t >> 4, q = t & 15;
  int node = (p < BB) ? u[p] : NU + ii[p - BB];
  float4 r;
  if (L0) {
    r = (node < NU) ? U4[(size_t)node * 16 + q] : V4[(size_t)(node - NU) * 16 + q];
  } else {
    r = E4[(size_t)node * 16 + q];
  }
  Es_l[p * 16 + q] = r;
}

// ---------------- attention precompute: M_h = Wk_h @ Wq_h^T (stored transposed),
//                  P_h = Wv_h @ Wo_h ----------------
__global__ void k_prep(const float* __restrict__ Wq, const float* __restrict__ Wk,
                       const float* __restrict__ Wv, const float* __restrict__ Wo,
                       float* __restrict__ Mt, float* __restrict__ P) {
  int t = blockIdx.x * 256 + threadIdx.x;
  if (t >= 16384) return;
  if (t < 8192) {
    int h = t >> 12;        // /4096
    int b = (t >> 6) & 63;  // e0-dim index
    int j = t & 63;         // output (g) index
    float s = 0.f;
    for (int k = 0; k < 32; ++k) s += Wk[j * 64 + h * 32 + k] * Wq[b * 64 + h * 32 + k];
    Mt[h * 4096 + b * 64 + j] = s;  // Mt[h][b][j] = M_h[j][b]
  } else {
    int t2 = t - 8192;
    int h = t2 >> 12;
    int d = (t2 >> 6) & 63;
    int j = t2 & 63;
    float s = 0.f;
    for (int v = 0; v < 32; ++v) s += Wv[d * 64 + h * 32 + v] * Wo[(h * 32 + v) * 64 + j];
    P[h * 4096 + d * 64 + j] = s;  // P[h][d][j]
  }
}

// ---------------- attention per node: wave per node, lane = dim ----------------
__global__ void k_attn2(const float* __restrict__ Es, const float* __restrict__ Mt,
                        const float* __restrict__ P, float* __restrict__ Eo) {
  __shared__ float sb[4][3 * 64];  // per wave: e0 bcast, Ebar0, Ebar1
  int wv = threadIdx.x >> 6, lane = threadIdx.x & 63;
  int p = blockIdx.x * 4 + wv;
  if (p >= NS) return;
  const float inv_scale = 0.17677669529663687f;  // 1/sqrt(32)

  float e0 = Es[(size_t)0 * NS * DD + p * DD + lane];
  float e1 = Es[(size_t)1 * NS * DD + p * DD + lane];
  float e2 = Es[(size_t)2 * NS * DD + p * DD + lane];
  float e3 = Es[(size_t)3 * NS * DD + p * DD + lane];
  sb[wv][lane] = e0;

  const float* M0 = Mt;
  const float* M1 = Mt + 4096;
  float g0 = 0.f, g1 = 0.f;
#pragma unroll 8
  for (int b = 0; b < 64; ++b) {
    float eb = sb[wv][b];  // LDS same-address broadcast
    g0 = fmaf(M0[b * 64 + lane], eb, g0);
    g1 = fmaf(M1[b * 64 + lane], eb, g1);
  }

  // scores[l][h] = (e_l . g_h) * inv_scale  — lane-aligned products, xor-tree reduce
  float el[4] = {e0, e1, e2, e3};
  float sc[4][2];
#pragma unroll
  for (int l = 0; l < 4; ++l) {
    float p0 = el[l] * g0, p1 = el[l] * g1;
#pragma unroll
    for (int o = 32; o; o >>= 1) {
      p0 += __shfl_xor(p0, o);
      p1 += __shfl_xor(p1, o);
    }
    sc[l][0] = p0 * inv_scale;
    sc[l][1] = p1 * inv_scale;
  }

  // softmax over l per head; Ebar_h[lane]
  float ebar[2];
#pragma unroll
  for (int h = 0; h < 2; ++h) {
    float m = fmaxf(fmaxf(sc[0][h], sc[1][h]), fmaxf(sc[2][h], sc[3][h]));
    float x0 = expf(sc[0][h] - m), x1 = expf(sc[1][h] - m);
    float x2 = expf(sc[2][h] - m), x3 = expf(sc[3][h] - m);
    float inv = 1.f / (x0 + x1 + x2 + x3);
    ebar[h] = (x0 * e0 + x1 * e1 + x2 * e2 + x3 * e3) * inv;
  }
  sb[wv][64 + lane] = ebar[0];
  sb[wv][128 + lane] = ebar[1];

  const float* P0 = P;
  const float* P1 = P + 4096;
  float o = 0.f;
#pragma unroll 8
  for (int d = 0; d < 64; ++d) {
    float b0 = sb[wv][64 + d];
    float b1 = sb[wv][128 + d];
    o = fmaf(P0[d * 64 + lane], b0, o);
    o = fmaf(P1[d * 64 + lane], b1, o);
  }
  Eo[(size_t)p * DD + lane] = o;
}

// final pair scoring
__global__ void k_dot(const float* __restrict__ Eo, float* __restrict__ out) {
  int w = (blockIdx.x * blockDim.x + threadIdx.x) >> 6;
  int lane = threadIdx.x & 63;
  if (w >= BB) return;
  float pd = Eo[(size_t)w * DD + lane] * Eo[(size_t)(BB + w) * DD + lane];
#pragma unroll
  for (int o = 32; o; o >>= 1) pd += __shfl_xor(pd, o);
  if (lane == 0) out[w] = pd;
}

extern "C" void kernel_launch(void* const* d_in, const int* in_sizes, int n_in,
                              void* d_out, int out_size, void* d_ws, size_t ws_size,
                              hipStream_t stream) {
  const int* edge_src = (const int*)d_in[0];
  const int* edge_dst = (const int*)d_in[1];
  const float* edge_val = (const float*)d_in[2];
  const float* U_emb = (const float*)d_in[3];
  const float* V_emb = (const float*)d_in[4];
  const float* Wq = (const float*)d_in[5];
  const float* Wk = (const float*)d_in[6];
  const float* Wv = (const float*)d_in[7];
  const float* Wo = (const float*)d_in[8];
  const int* u = (const int*)d_in[9];
  const int* ii = (const int*)d_in[10];
  float* out = (float*)d_out;

  const float4* U4 = (const float4*)U_emb;
  const float4* V4 = (const float4*)V_emb;

  // workspace layout (16B-aligned base)
  float* Ea = (float*)d_ws;                          // NN*64  (E1)
  float* Eb = Ea + (size_t)NN * DD;                  // NN*64  (E2)
  float* Es = Eb + (size_t)NN * DD;                  // 4*NS*64
  float* Eo = Es + (size_t)4 * NS * DD;              // NS*64
  float* Mt = Eo + (size_t)NS * DD;                  // 2*4096
  float* Pm = Mt + 8192;                             // 2*4096
  int* row_ptr = (int*)(Pm + 8192);                  // NN+1
  int* cursor = row_ptr + NN + 1;                    // NN
  int* bsums = cursor + NN;                          // 1024
  int* need1 = bsums + 1024;                         // NN
  int* need2 = need1 + NN;                           // NN
  uintptr_t pa = (uintptr_t)(need2 + NN);
  pa = (pa + 15) & ~(uintptr_t)15;
  int2* pairs = (int2*)pa;                           // NE int2

  float4* Ea4 = (float4*)Ea;
  float4* Eb4 = (float4*)Eb;
  float4* Es4 = (float4*)Es;

  // attention weight precompute (independent of graph work)
  k_prep<<<64, 256, 0, stream>>>(Wq, Wk, Wv, Wo, Mt, Pm);

  // CSR build (counts use `cursor` storage)
  hipMemsetAsync(cursor, 0, NN * sizeof(int), stream);
  hipMemsetAsync(need1, 0, 2 * NN * sizeof(int), stream);
  k_hist<<<(NE + 255) / 256, 256, 0, stream>>>(edge_dst, cursor);
  int nblk = (NN + 255) / 256;  // 782
  k_scan_blocks<<<nblk, 256, 0, stream>>>(cursor, row_ptr, bsums);
  k_scan_top<<<1, 1024, 0, stream>>>(bsums, nblk);
  k_add_off<<<nblk, 256, 0, stream>>>(row_ptr, bsums);
  hipMemsetAsync(cursor, 0, NN * sizeof(int), stream);
  k_scatter<<<(NE + 255) / 256, 256, 0, stream>>>(edge_src, edge_dst, edge_val, row_ptr, cursor,
                                                  pairs);

  // frontier marking
  k_mark_s<<<(NS + 255) / 256, 256, 0, stream>>>(u, ii, row_ptr, pairs, need1, need2);
  k_mark2<<<nblk, 256, 0, stream>>>(row_ptr, pairs, need2, need1);

  int ggrid = (NS * 16 + 255) / 256;
  int pgrid = (NN * 64 + 255) / 256;

  k_gather<1><<<ggrid, 256, 0, stream>>>(U4, V4, nullptr, Es4 + (size_t)0 * NS * 16, u, ii);
  k_prop4<1><<<pgrid, 256, 0, stream>>>(U4, V4, nullptr, Ea4, row_ptr, pairs, need1);
  k_gather<0><<<ggrid, 256, 0, stream>>>(nullptr, nullptr, Ea4, Es4 + (size_t)1 * NS * 16, u, ii);
  k_prop4<0><<<pgrid, 256, 0, stream>>>(nullptr, nullptr, Ea4, Eb4, row_ptr, pairs, need2);
  k_gather<0><<<ggrid, 256, 0, stream>>>(nullptr, nullptr, Eb4, Es4 + (size_t)2 * NS * 16, u, ii);
  k_prop3<<<(NS * 64 + 255) / 256, 256, 0, stream>>>(Eb4, Es4 + (size_t)3 * NS * 16, row_ptr,
                                                     pairs, u, ii);

  k_attn2<<<(NS + 3) / 4, 256, 0, stream>>>(Es, Mt, Pm, Eo);
  k_dot<<<(BB * 64 + 255) / 256, 256, 0, stream>>>(Eo, out);
}

// Round 4
// 287.344 us; speedup vs baseline: 2.2843x; 1.0748x over previous
//
#include <hip/hip_runtime.h>

#define NU 120000
#define NI 80000
#define NN 200000
#define DD 64
#define NE 1280000
#define BB 4096
#define NS 8192   // 2*B sampled nodes
#define NB 782    // ceil(NN/256) buckets, bucket = dst>>8
#define CHUNK 8192

// ---------------- CSR build: hist + scan ----------------
__global__ void k_hist(const int* __restrict__ dst, int* __restrict__ counts) {
  int e = blockIdx.x * blockDim.x + threadIdx.x;
  if (e < NE) atomicAdd(&counts[dst[e]], 1);
}

__global__ void k_scan_blocks(const int* __restrict__ counts, int* __restrict__ row_ptr,
                              int* __restrict__ bsums) {
  __shared__ int s[256];
  int i = blockIdx.x * 256 + threadIdx.x;
  int x = (i < NN) ? counts[i] : 0;
  s[threadIdx.x] = x;
  __syncthreads();
  for (int off = 1; off < 256; off <<= 1) {
    int t = (threadIdx.x >= off) ? s[threadIdx.x - off] : 0;
    __syncthreads();
    s[threadIdx.x] += t;
    __syncthreads();
  }
  if (i < NN) row_ptr[i] = s[threadIdx.x] - x;  // exclusive
  if (threadIdx.x == 255) bsums[blockIdx.x] = s[255];
}

__global__ void k_scan_top(int* __restrict__ bsums, int nblk) {
  __shared__ int s[1024];
  int x = (threadIdx.x < nblk) ? bsums[threadIdx.x] : 0;
  s[threadIdx.x] = x;
  __syncthreads();
  for (int off = 1; off < 1024; off <<= 1) {
    int t = (threadIdx.x >= off) ? s[threadIdx.x - off] : 0;
    __syncthreads();
    s[threadIdx.x] += t;
    __syncthreads();
  }
  if (threadIdx.x < nblk) bsums[threadIdx.x] = s[threadIdx.x] - x;  // exclusive
}

__global__ void k_add_off(int* __restrict__ row_ptr, const int* __restrict__ bsums) {
  int i = blockIdx.x * 256 + threadIdx.x;
  if (i < NN) row_ptr[i] += bsums[blockIdx.x];
  if (i == 0) row_ptr[NN] = NE;
}

__global__ void k_init_cur(const int* __restrict__ row_ptr, int* __restrict__ bcur) {
  int b = blockIdx.x * 256 + threadIdx.x;
  if (b < NB) bcur[b] = row_ptr[b << 8];
}

// ---------------- two-phase bucketed scatter ----------------
// Phase 1: bin edges into 782 dst-buckets, bucket-contiguous scratch writes.
__global__ void k_coarse(const int* __restrict__ src, const int* __restrict__ dst,
                         const float* __restrict__ val, int* __restrict__ bcur,
                         int2* __restrict__ c_sv, int* __restrict__ c_dst) {
  __shared__ int hist[NB];
  __shared__ int base[NB];
  int tid = threadIdx.x;
  int e0 = blockIdx.x * CHUNK;
  for (int i = tid; i < NB; i += 256) hist[i] = 0;
  __syncthreads();
#pragma unroll
  for (int k = 0; k < CHUNK / 256; ++k) {
    int e = e0 + k * 256 + tid;
    if (e < NE) atomicAdd(&hist[dst[e] >> 8], 1);
  }
  __syncthreads();
  for (int i = tid; i < NB; i += 256) {
    int h = hist[i];
    base[i] = h ? atomicAdd(&bcur[i], h) : 0;
    hist[i] = 0;
  }
  __syncthreads();
#pragma unroll
  for (int k = 0; k < CHUNK / 256; ++k) {
    int e = e0 + k * 256 + tid;
    if (e < NE) {
      int d = dst[e];
      int b = d >> 8;
      int pos = base[b] + atomicAdd(&hist[b], 1);
      c_sv[pos] = make_int2(src[e], __float_as_int(val[e]));
      c_dst[pos] = d;
    }
  }
}

// Phase 2: one block per bucket; final CSR position via LDS per-node cursors.
__global__ void k_fine(const int* __restrict__ row_ptr, const int2* __restrict__ c_sv,
                       const int* __restrict__ c_dst, int2* __restrict__ pairs) {
  __shared__ int cur[256];
  int b = blockIdx.x;
  int node0 = b << 8;
  cur[threadIdx.x] = 0;
  __syncthreads();
  int start = row_ptr[node0];
  int hi = node0 + 256;
  int end = row_ptr[hi > NN ? NN : hi];
  for (int e = start + threadIdx.x; e < end; e += 256) {
    int d = c_dst[e];
    int2 sv = c_sv[e];
    int off = atomicAdd(&cur[d - node0], 1);
    pairs[row_ptr[d] + off] = sv;
  }
}

// ---------------- frontier marking ----------------
__global__ void k_mark_s(const int* __restrict__ u, const int* __restrict__ ii,
                         const int* __restrict__ row_ptr, const int2* __restrict__ pairs,
                         int* __restrict__ need1, int* __restrict__ need2) {
  int t = blockIdx.x * blockDim.x + threadIdx.x;
  if (t >= NS) return;
  int node = (t < BB) ? u[t] : NU + ii[t - BB];
  need2[node] = 1;
  need1[node] = 1;
  int s = row_ptr[node], e = row_ptr[node + 1];
  for (int j = s; j < e; ++j) need2[pairs[j].x] = 1;
}

__global__ void k_mark2(const int* __restrict__ row_ptr, const int2* __restrict__ pairs,
                        const int* __restrict__ need2, int* __restrict__ need1) {
  int n = blockIdx.x * blockDim.x + threadIdx.x;
  if (n >= NN || !need2[n]) return;
  int s = row_ptr[n], e = row_ptr[n + 1];
  for (int j = s; j < e; ++j) need1[pairs[j].x] = 1;
}

// ---------------- propagation: one wave per node, 4 edges x 16 dim-chunks ----------------
template <int L0>
__global__ void k_prop4(const float4* __restrict__ U4, const float4* __restrict__ V4,
                        const float4* __restrict__ E4in, float4* __restrict__ E4out,
                        const int* __restrict__ row_ptr, const int2* __restrict__ pairs,
                        const int* __restrict__ need) {
  int wid = (blockIdx.x * blockDim.x + threadIdx.x) >> 6;
  if (wid >= NN) return;
  if (!need[wid]) return;
  int lane = threadIdx.x & 63;
  int sub = lane >> 4, c = lane & 15;
  int start = row_ptr[wid], end = row_ptr[wid + 1];
  float4 acc = make_float4(0.f, 0.f, 0.f, 0.f);
  for (int j0 = start; j0 < end; j0 += 4) {
    int j = j0 + sub;
    bool ok = j < end;
    int jj = ok ? j : start;
    int2 pv = pairs[jj];
    float v = ok ? __int_as_float(pv.y) : 0.f;
    int s = pv.x;
    const float4* base;
    if (L0) {
      base = (s < NU) ? (U4 + (size_t)s * 16) : (V4 + (size_t)(s - NU) * 16);
    } else {
      base = E4in + (size_t)s * 16;
    }
    float4 r = base[c];
    acc.x += v * r.x;
    acc.y += v * r.y;
    acc.z += v * r.z;
    acc.w += v * r.w;
  }
#pragma unroll
  for (int off = 16; off <= 32; off <<= 1) {
    acc.x += __shfl_xor(acc.x, off);
    acc.y += __shfl_xor(acc.y, off);
    acc.z += __shfl_xor(acc.z, off);
    acc.w += __shfl_xor(acc.w, off);
  }
  if (sub == 0) E4out[(size_t)wid * 16 + c] = acc;
}

// prop layer 3: only the 8192 sampled nodes, writes Es[3] directly
__global__ void k_prop3(const float4* __restrict__ E4in, float4* __restrict__ Es3,
                        const int* __restrict__ row_ptr, const int2* __restrict__ pairs,
                        const int* __restrict__ u, const int* __restrict__ ii) {
  int wid = (blockIdx.x * blockDim.x + threadIdx.x) >> 6;
  if (wid >= NS) return;
  int node = (wid < BB) ? u[wid] : NU + ii[wid - BB];
  int lane = threadIdx.x & 63;
  int sub = lane >> 4, c = lane & 15;
  int start = row_ptr[node], end = row_ptr[node + 1];
  float4 acc = make_float4(0.f, 0.f, 0.f, 0.f);
  for (int j0 = start; j0 < end; j0 += 4) {
    int j = j0 + sub;
    bool ok = j < end;
    int jj = ok ? j : start;
    int2 pv = pairs[jj];
    float v = ok ? __int_as_float(pv.y) : 0.f;
    float4 r = E4in[(size_t)pv.x * 16 + c];
    acc.x += v * r.x;
    acc.y += v * r.y;
    acc.z += v * r.z;
    acc.w += v * r.w;
  }
#pragma unroll
  for (int off = 16; off <= 32; off <<= 1) {
    acc.x += __shfl_xor(acc.x, off);
    acc.y += __shfl_xor(acc.y, off);
    acc.z += __shfl_xor(acc.z, off);
    acc.w += __shfl_xor(acc.w, off);
  }
  if (sub == 0) Es3[(size_t)wid * 16 + c] = acc;
}

// gather sampled nodes for one layer into Es[l] (NS x 64). L0: virtual concat of U/V.
template <int L0>
__global__ void k_gather(const float4* __restrict__ U4, const float4* __restrict__ V4,
                         const float4* __restrict__ E4, float4* __restrict__ Es_l,
                         const int* __restrict__ u, const int* __restrict__ ii) {
  int t = blockIdx.x * blockDim.x + threadIdx.x;
  if (t >= NS * 16) return;
  int p = t >> 4, q = t & 15;
  int node = (p < BB) ? u[p] : NU + ii[p - BB];
  float4 r;
  if (L0) {
    r = (node < NU) ? U4[(size_t)node * 16 + q] : V4[(size_t)(node - NU) * 16 + q];
  } else {
    r = E4[(size_t)node * 16 + q];
  }
  Es_l[p * 16 + q] = r;
}

// ---------------- attention precompute: Mt[h][b][j] = (Wk_h Wq_h^T)[j][b], P[h][d][j] ----------------
__global__ void k_prep(const float* __restrict__ Wq, const float* __restrict__ Wk,
                       const float* __restrict__ Wv, const float* __restrict__ Wo,
                       float* __restrict__ Mt, float* __restrict__ P) {
  int t = blockIdx.x * 256 + threadIdx.x;
  if (t >= 16384) return;
  if (t < 8192) {
    int h = t >> 12;
    int b = (t >> 6) & 63;
    int j = t & 63;
    float s = 0.f;
    for (int k = 0; k < 32; ++k) s += Wk[j * 64 + h * 32 + k] * Wq[b * 64 + h * 32 + k];
    Mt[h * 4096 + b * 64 + j] = s;
  } else {
    int t2 = t - 8192;
    int h = t2 >> 12;
    int d = (t2 >> 6) & 63;
    int j = t2 & 63;
    float s = 0.f;
    for (int v = 0; v < 32; ++v) s += Wv[d * 64 + h * 32 + v] * Wo[(h * 32 + v) * 64 + j];
    P[h * 4096 + d * 64 + j] = s;
  }
}

// ---------------- attention per node: wave per node, lane = dim ----------------
__global__ void k_attn2(const float* __restrict__ Es, const float* __restrict__ Mt,
                        const float* __restrict__ P, float* __restrict__ Eo) {
  __shared__ float sb[4][3 * 64];
  int wv = threadIdx.x >> 6, lane = threadIdx.x & 63;
  int p = blockIdx.x * 4 + wv;
  if (p >= NS) return;
  const float inv_scale = 0.17677669529663687f;  // 1/sqrt(32)

  float e0 = Es[(size_t)0 * NS * DD + p * DD + lane];
  float e1 = Es[(size_t)1 * NS * DD + p * DD + lane];
  float e2 = Es[(size_t)2 * NS * DD + p * DD + lane];
  float e3 = Es[(size_t)3 * NS * DD + p * DD + lane];
  sb[wv][lane] = e0;

  const float* M0 = Mt;
  const float* M1 = Mt + 4096;
  float g0 = 0.f, g1 = 0.f;
#pragma unroll 8
  for (int b = 0; b < 64; ++b) {
    float eb = sb[wv][b];
    g0 = fmaf(M0[b * 64 + lane], eb, g0);
    g1 = fmaf(M1[b * 64 + lane], eb, g1);
  }

  float el[4] = {e0, e1, e2, e3};
  float sc[4][2];
#pragma unroll
  for (int l = 0; l < 4; ++l) {
    float p0 = el[l] * g0, p1 = el[l] * g1;
#pragma unroll
    for (int o = 32; o; o >>= 1) {
      p0 += __shfl_xor(p0, o);
      p1 += __shfl_xor(p1, o);
    }
    sc[l][0] = p0 * inv_scale;
    sc[l][1] = p1 * inv_scale;
  }

  float ebar[2];
#pragma unroll
  for (int h = 0; h < 2; ++h) {
    float m = fmaxf(fmaxf(sc[0][h], sc[1][h]), fmaxf(sc[2][h], sc[3][h]));
    float x0 = expf(sc[0][h] - m), x1 = expf(sc[1][h] - m);
    float x2 = expf(sc[2][h] - m), x3 = expf(sc[3][h] - m);
    float inv = 1.f / (x0 + x1 + x2 + x3);
    ebar[h] = (x0 * e0 + x1 * e1 + x2 * e2 + x3 * e3) * inv;
  }
  sb[wv][64 + lane] = ebar[0];
  sb[wv][128 + lane] = ebar[1];

  const float* P0 = P;
  const float* P1 = P + 4096;
  float o = 0.f;
#pragma unroll 8
  for (int d = 0; d < 64; ++d) {
    float b0 = sb[wv][64 + d];
    float b1 = sb[wv][128 + d];
    o = fmaf(P0[d * 64 + lane], b0, o);
    o = fmaf(P1[d * 64 + lane], b1, o);
  }
  Eo[(size_t)p * DD + lane] = o;
}

// final pair scoring
__global__ void k_dot(const float* __restrict__ Eo, float* __restrict__ out) {
  int w = (blockIdx.x * blockDim.x + threadIdx.x) >> 6;
  int lane = threadIdx.x & 63;
  if (w >= BB) return;
  float pd = Eo[(size_t)w * DD + lane] * Eo[(size_t)(BB + w) * DD + lane];
#pragma unroll
  for (int o = 32; o; o >>= 1) pd += __shfl_xor(pd, o);
  if (lane == 0) out[w] = pd;
}

extern "C" void kernel_launch(void* const* d_in, const int* in_sizes, int n_in,
                              void* d_out, int out_size, void* d_ws, size_t ws_size,
                              hipStream_t stream) {
  const int* edge_src = (const int*)d_in[0];
  const int* edge_dst = (const int*)d_in[1];
  const float* edge_val = (const float*)d_in[2];
  const float* U_emb = (const float*)d_in[3];
  const float* V_emb = (const float*)d_in[4];
  const float* Wq = (const float*)d_in[5];
  const float* Wk = (const float*)d_in[6];
  const float* Wv = (const float*)d_in[7];
  const float* Wo = (const float*)d_in[8];
  const int* u = (const int*)d_in[9];
  const int* ii = (const int*)d_in[10];
  float* out = (float*)d_out;

  const float4* U4 = (const float4*)U_emb;
  const float4* V4 = (const float4*)V_emb;

  // workspace layout (16B-aligned base)
  float* Ea = (float*)d_ws;                          // NN*64  (E1; coarse scratch sv before)
  float* Eb = Ea + (size_t)NN * DD;                  // NN*64  (E2; coarse scratch dst before)
  float* Es = Eb + (size_t)NN * DD;                  // 4*NS*64
  float* Eo = Es + (size_t)4 * NS * DD;              // NS*64
  float* Mt = Eo + (size_t)NS * DD;                  // 2*4096
  float* Pm = Mt + 8192;                             // 2*4096
  int* row_ptr = (int*)(Pm + 8192);                  // NN+1
  int* counts = row_ptr + NN + 1;                    // NN
  int* bsums = counts + NN;                          // 1024
  int* need1 = bsums + 1024;                         // NN
  int* need2 = need1 + NN;                           // NN
  int* bcur = need2 + NN;                            // NB
  uintptr_t pa = (uintptr_t)(bcur + NB);
  pa = (pa + 15) & ~(uintptr_t)15;
  int2* pairs = (int2*)pa;                           // NE int2

  int2* c_sv = (int2*)Ea;   // NE int2 (10.2MB) — dead before E1 write
  int* c_dst = (int*)Eb;    // NE int  (5.1MB)  — dead before E2 write

  float4* Ea4 = (float4*)Ea;
  float4* Eb4 = (float4*)Eb;
  float4* Es4 = (float4*)Es;

  // attention weight precompute (independent of graph work)
  k_prep<<<64, 256, 0, stream>>>(Wq, Wk, Wv, Wo, Mt, Pm);

  // CSR build
  hipMemsetAsync(counts, 0, NN * sizeof(int), stream);
  hipMemsetAsync(need1, 0, 2 * NN * sizeof(int), stream);
  k_hist<<<(NE + 255) / 256, 256, 0, stream>>>(edge_dst, counts);
  int nblk = (NN + 255) / 256;  // 782
  k_scan_blocks<<<nblk, 256, 0, stream>>>(counts, row_ptr, bsums);
  k_scan_top<<<1, 1024, 0, stream>>>(bsums, nblk);
  k_add_off<<<nblk, 256, 0, stream>>>(row_ptr, bsums);
  k_init_cur<<<(NB + 255) / 256, 256, 0, stream>>>(row_ptr, bcur);

  // two-phase bucketed scatter
  k_coarse<<<(NE + CHUNK - 1) / CHUNK, 256, 0, stream>>>(edge_src, edge_dst, edge_val, bcur,
                                                         c_sv, c_dst);
  k_fine<<<NB, 256, 0, stream>>>(row_ptr, c_sv, c_dst, pairs);

  // frontier marking
  k_mark_s<<<(NS + 255) / 256, 256, 0, stream>>>(u, ii, row_ptr, pairs, need1, need2);
  k_mark2<<<nblk, 256, 0, stream>>>(row_ptr, pairs, need2, need1);

  int ggrid = (NS * 16 + 255) / 256;
  int pgrid = (NN * 64 + 255) / 256;

  k_gather<1><<<ggrid, 256, 0, stream>>>(U4, V4, nullptr, Es4 + (size_t)0 * NS * 16, u, ii);
  k_prop4<1><<<pgrid, 256, 0, stream>>>(U4, V4, nullptr, Ea4, row_ptr, pairs, need1);
  k_gather<0><<<ggrid, 256, 0, stream>>>(nullptr, nullptr, Ea4, Es4 + (size_t)1 * NS * 16, u, ii);
  k_prop4<0><<<pgrid, 256, 0, stream>>>(nullptr, nullptr, Ea4, Eb4, row_ptr, pairs, need2);
  k_gather<0><<<ggrid, 256, 0, stream>>>(nullptr, nullptr, Eb4, Es4 + (size_t)2 * NS * 16, u, ii);
  k_prop3<<<(NS * 64 + 255) / 256, 256, 0, stream>>>(Eb4, Es4 + (size_t)3 * NS * 16, row_ptr,
                                                     pairs, u, ii);

  k_attn2<<<(NS + 3) / 4, 256, 0, stream>>>(Es, Mt, Pm, Eo);
  k_dot<<<(BB * 64 + 255) / 256, 256, 0, stream>>>(Eo, out);
}

// Round 5
// 227.525 us; speedup vs baseline: 2.8848x; 1.2629x over previous
//
#include <hip/hip_runtime.h>

#define NU 120000
#define NI 80000
#define NN 200000
#define DD 64
#define NE 1280000
#define BB 4096
#define NS 8192   // 2*B sampled nodes
#define NB 782    // ceil(NN/256) buckets, bucket = dst>>8
#define CHUNK 8192

// ---------------- bucket histogram (782 LDS counters, merge via global atomics) ----------------
__global__ void k_bhist(const int* __restrict__ dst, int* __restrict__ bcount) {
  __shared__ int h[NB];
  for (int i = threadIdx.x; i < NB; i += 256) h[i] = 0;
  __syncthreads();
  int e0 = blockIdx.x * CHUNK;
#pragma unroll
  for (int k = 0; k < CHUNK / 256; ++k) {
    int e = e0 + k * 256 + threadIdx.x;
    if (e < NE) atomicAdd(&h[dst[e] >> 8], 1);
  }
  __syncthreads();
  for (int i = threadIdx.x; i < NB; i += 256)
    if (h[i]) atomicAdd(&bcount[i], h[i]);
}

// single-block scan of 782 bucket counts -> bbase (exclusive), init bcur
__global__ void k_bscan(const int* __restrict__ bcount, int* __restrict__ bbase,
                        int* __restrict__ bcur, int* __restrict__ row_ptr) {
  __shared__ int s[1024];
  int t = threadIdx.x;
  int x = (t < NB) ? bcount[t] : 0;
  s[t] = x;
  __syncthreads();
  for (int off = 1; off < 1024; off <<= 1) {
    int v = (t >= off) ? s[t - off] : 0;
    __syncthreads();
    s[t] += v;
    __syncthreads();
  }
  if (t < NB) {
    int e = s[t] - x;
    bbase[t] = e;
    bcur[t] = e;
  }
  if (t == 0) {
    bbase[NB] = NE;
    row_ptr[NN] = NE;
  }
}

// ---------------- two-phase bucketed scatter ----------------
// Phase 1: bin edges into 782 dst-buckets, bucket-contiguous scratch writes.
__global__ void k_coarse(const int* __restrict__ src, const int* __restrict__ dst,
                         const float* __restrict__ val, int* __restrict__ bcur,
                         int2* __restrict__ c_sv, int* __restrict__ c_dst) {
  __shared__ int hist[NB];
  __shared__ int base[NB];
  int tid = threadIdx.x;
  int e0 = blockIdx.x * CHUNK;
  for (int i = tid; i < NB; i += 256) hist[i] = 0;
  __syncthreads();
#pragma unroll
  for (int k = 0; k < CHUNK / 256; ++k) {
    int e = e0 + k * 256 + tid;
    if (e < NE) atomicAdd(&hist[dst[e] >> 8], 1);
  }
  __syncthreads();
  for (int i = tid; i < NB; i += 256) {
    int h = hist[i];
    base[i] = h ? atomicAdd(&bcur[i], h) : 0;
    hist[i] = 0;
  }
  __syncthreads();
#pragma unroll
  for (int k = 0; k < CHUNK / 256; ++k) {
    int e = e0 + k * 256 + tid;
    if (e < NE) {
      int d = dst[e];
      int b = d >> 8;
      int pos = base[b] + atomicAdd(&hist[b], 1);
      c_sv[pos] = make_int2(src[e], __float_as_int(val[e]));
      c_dst[pos] = d;
    }
  }
}

// Phase 2: one block per bucket; per-node counts+scan in LDS; writes row_ptr AND pairs.
__global__ void k_fine2(const int* __restrict__ bbase, const int2* __restrict__ c_sv,
                        const int* __restrict__ c_dst, int2* __restrict__ pairs,
                        int* __restrict__ row_ptr) {
  __shared__ int cnt[256];
  __shared__ int pre[256];
  __shared__ int cur[256];
  int b = blockIdx.x;
  int node0 = b << 8;
  int t = threadIdx.x;
  cnt[t] = 0;
  __syncthreads();
  int start = bbase[b], end = bbase[b + 1];
  for (int e = start + t; e < end; e += 256) atomicAdd(&cnt[c_dst[e] - node0], 1);
  __syncthreads();
  int x = cnt[t];
  pre[t] = x;
  __syncthreads();
  for (int off = 1; off < 256; off <<= 1) {
    int v = (t >= off) ? pre[t - off] : 0;
    __syncthreads();
    pre[t] += v;
    __syncthreads();
  }
  int node = node0 + t;
  if (node < NN) row_ptr[node] = start + pre[t] - x;  // exclusive prefix
  cur[t] = 0;
  __syncthreads();
  for (int e = start + t; e < end; e += 256) {
    int d = c_dst[e];
    int loc = d - node0;
    int off = atomicAdd(&cur[loc], 1);
    pairs[start + pre[loc] - cnt[loc] + off] = c_sv[e];
  }
}

// ---------------- frontier marking ----------------
__global__ void k_mark_s(const int* __restrict__ u, const int* __restrict__ ii,
                         const int* __restrict__ row_ptr, const int2* __restrict__ pairs,
                         int* __restrict__ need1, int* __restrict__ need2) {
  int t = blockIdx.x * blockDim.x + threadIdx.x;
  if (t >= NS) return;
  int node = (t < BB) ? u[t] : NU + ii[t - BB];
  need2[node] = 1;
  need1[node] = 1;
  int s = row_ptr[node], e = row_ptr[node + 1];
  for (int j = s; j < e; ++j) need2[pairs[j].x] = 1;
}

__global__ void k_mark2(const int* __restrict__ row_ptr, const int2* __restrict__ pairs,
                        const int* __restrict__ need2, int* __restrict__ need1) {
  int n = blockIdx.x * blockDim.x + threadIdx.x;
  if (n >= NN || !need2[n]) return;
  int s = row_ptr[n], e = row_ptr[n + 1];
  for (int j = s; j < e; ++j) need1[pairs[j].x] = 1;
}

// ---------------- propagation: wave per node, 16-edge tiles, decoupled index load ----------------
// lanes 0-15 hold the tile's pairs; sub=lane>>4 picks edge k*4+sub; c=lane&15 is the float4 chunk.
template <int L0>
__global__ void k_prop4(const float4* __restrict__ U4, const float4* __restrict__ V4,
                        const float4* __restrict__ E4in, float4* __restrict__ E4out,
                        const int* __restrict__ row_ptr, const int2* __restrict__ pairs,
                        const int* __restrict__ need) {
  int wid = (blockIdx.x * blockDim.x + threadIdx.x) >> 6;
  if (wid >= NN) return;
  if (!need[wid]) return;
  int lane = threadIdx.x & 63;
  int sub = lane >> 4, c = lane & 15;
  int lidx = lane & 15;
  int start = row_ptr[wid], end = row_ptr[wid + 1];
  float4 acc = make_float4(0.f, 0.f, 0.f, 0.f);
  for (int t0 = start; t0 < end; t0 += 16) {
    int cap = end - t0;
    if (cap > 16) cap = 16;
    int2 mp = pairs[t0 + (lidx < cap ? lidx : 0)];  // one coalesced tile-index load
    float4 r[4];
    float vv[4];
#pragma unroll
    for (int k = 0; k < 4; ++k) {
      int idx = k * 4 + sub;
      int s = __shfl(mp.x, idx);
      float v = __int_as_float(__shfl(mp.y, idx));
      vv[k] = (idx < cap) ? v : 0.f;
      const float4* base;
      if (L0) {
        base = (s < NU) ? (U4 + (size_t)s * 16) : (V4 + (size_t)(s - NU) * 16);
      } else {
        base = E4in + (size_t)s * 16;
      }
      r[k] = base[c];  // 4 independent gathers in flight per lane
    }
#pragma unroll
    for (int k = 0; k < 4; ++k) {
      acc.x += vv[k] * r[k].x;
      acc.y += vv[k] * r[k].y;
      acc.z += vv[k] * r[k].z;
      acc.w += vv[k] * r[k].w;
    }
  }
#pragma unroll
  for (int off = 16; off <= 32; off <<= 1) {
    acc.x += __shfl_xor(acc.x, off);
    acc.y += __shfl_xor(acc.y, off);
    acc.z += __shfl_xor(acc.z, off);
    acc.w += __shfl_xor(acc.w, off);
  }
  if (sub == 0) E4out[(size_t)wid * 16 + c] = acc;
}

// prop layer 3: only the 8192 sampled nodes, writes Es[3] directly
__global__ void k_prop3(const float4* __restrict__ E4in, float4* __restrict__ Es3,
                        const int* __restrict__ row_ptr, const int2* __restrict__ pairs,
                        const int* __restrict__ u, const int* __restrict__ ii) {
  int wid = (blockIdx.x * blockDim.x + threadIdx.x) >> 6;
  if (wid >= NS) return;
  int node = (wid < BB) ? u[wid] : NU + ii[wid - BB];
  int lane = threadIdx.x & 63;
  int sub = lane >> 4, c = lane & 15;
  int lidx = lane & 15;
  int start = row_ptr[node], end = row_ptr[node + 1];
  float4 acc = make_float4(0.f, 0.f, 0.f, 0.f);
  for (int t0 = start; t0 < end; t0 += 16) {
    int cap = end - t0;
    if (cap > 16) cap = 16;
    int2 mp = pairs[t0 + (lidx < cap ? lidx : 0)];
    float4 r[4];
    float vv[4];
#pragma unroll
    for (int k = 0; k < 4; ++k) {
      int idx = k * 4 + sub;
      int s = __shfl(mp.x, idx);
      float v = __int_as_float(__shfl(mp.y, idx));
      vv[k] = (idx < cap) ? v : 0.f;
      r[k] = E4in[(size_t)s * 16 + c];
    }
#pragma unroll
    for (int k = 0; k < 4; ++k) {
      acc.x += vv[k] * r[k].x;
      acc.y += vv[k] * r[k].y;
      acc.z += vv[k] * r[k].z;
      acc.w += vv[k] * r[k].w;
    }
  }
#pragma unroll
  for (int off = 16; off <= 32; off <<= 1) {
    acc.x += __shfl_xor(acc.x, off);
    acc.y += __shfl_xor(acc.y, off);
    acc.z += __shfl_xor(acc.z, off);
    acc.w += __shfl_xor(acc.w, off);
  }
  if (sub == 0) Es3[(size_t)wid * 16 + c] = acc;
}

// gather sampled nodes for one layer into Es[l] (NS x 64). L0: virtual concat of U/V.
template <int L0>
__global__ void k_gather(const float4* __restrict__ U4, const float4* __restrict__ V4,
                         const float4* __restrict__ E4, float4* __restrict__ Es_l,
                         const int* __restrict__ u, const int* __restrict__ ii) {
  int t = blockIdx.x * blockDim.x + threadIdx.x;
  if (t >= NS * 16) return;
  int p = t >> 4, q = t & 15;
  int node = (p < BB) ? u[p] : NU + ii[p - BB];
  float4 r;
  if (L0) {
    r = (node < NU) ? U4[(size_t)node * 16 + q] : V4[(size_t)(node - NU) * 16 + q];
  } else {
    r = E4[(size_t)node * 16 + q];
  }
  Es_l[p * 16 + q] = r;
}

// ---------------- attention precompute: Mt[h][b][j] = (Wk_h Wq_h^T)[j][b], P[h][d][j] ----------------
__global__ void k_prep(const float* __restrict__ Wq, const float* __restrict__ Wk,
                       const float* __restrict__ Wv, const float* __restrict__ Wo,
                       float* __restrict__ Mt, float* __restrict__ P) {
  int t = blockIdx.x * 256 + threadIdx.x;
  if (t >= 16384) return;
  if (t < 8192) {
    int h = t >> 12;
    int b = (t >> 6) & 63;
    int j = t & 63;
    float s = 0.f;
    for (int k = 0; k < 32; ++k) s += Wk[j * 64 + h * 32 + k] * Wq[b * 64 + h * 32 + k];
    Mt[h * 4096 + b * 64 + j] = s;
  } else {
    int t2 = t - 8192;
    int h = t2 >> 12;
    int d = (t2 >> 6) & 63;
    int j = t2 & 63;
    float s = 0.f;
    for (int v = 0; v < 32; ++v) s += Wv[d * 64 + h * 32 + v] * Wo[(h * 32 + v) * 64 + j];
    P[h * 4096 + d * 64 + j] = s;
  }
}

// ---------------- attention per node: wave per node, lane = dim ----------------
__global__ void k_attn2(const float* __restrict__ Es, const float* __restrict__ Mt,
                        const float* __restrict__ P, float* __restrict__ Eo) {
  __shared__ float sb[4][3 * 64];
  int wv = threadIdx.x >> 6, lane = threadIdx.x & 63;
  int p = blockIdx.x * 4 + wv;
  if (p >= NS) return;
  const float inv_scale = 0.17677669529663687f;  // 1/sqrt(32)

  float e0 = Es[(size_t)0 * NS * DD + p * DD + lane];
  float e1 = Es[(size_t)1 * NS * DD + p * DD + lane];
  float e2 = Es[(size_t)2 * NS * DD + p * DD + lane];
  float e3 = Es[(size_t)3 * NS * DD + p * DD + lane];
  sb[wv][lane] = e0;

  const float* M0 = Mt;
  const float* M1 = Mt + 4096;
  float g0 = 0.f, g1 = 0.f;
#pragma unroll 8
  for (int b = 0; b < 64; ++b) {
    float eb = sb[wv][b];
    g0 = fmaf(M0[b * 64 + lane], eb, g0);
    g1 = fmaf(M1[b * 64 + lane], eb, g1);
  }

  float el[4] = {e0, e1, e2, e3};
  float sc[4][2];
#pragma unroll
  for (int l = 0; l < 4; ++l) {
    float p0 = el[l] * g0, p1 = el[l] * g1;
#pragma unroll
    for (int o = 32; o; o >>= 1) {
      p0 += __shfl_xor(p0, o);
      p1 += __shfl_xor(p1, o);
    }
    sc[l][0] = p0 * inv_scale;
    sc[l][1] = p1 * inv_scale;
  }

  float ebar[2];
#pragma unroll
  for (int h = 0; h < 2; ++h) {
    float m = fmaxf(fmaxf(sc[0][h], sc[1][h]), fmaxf(sc[2][h], sc[3][h]));
    float x0 = expf(sc[0][h] - m), x1 = expf(sc[1][h] - m);
    float x2 = expf(sc[2][h] - m), x3 = expf(sc[3][h] - m);
    float inv = 1.f / (x0 + x1 + x2 + x3);
    ebar[h] = (x0 * e0 + x1 * e1 + x2 * e2 + x3 * e3) * inv;
  }
  sb[wv][64 + lane] = ebar[0];
  sb[wv][128 + lane] = ebar[1];

  const float* P0 = P;
  const float* P1 = P + 4096;
  float o = 0.f;
#pragma unroll 8
  for (int d = 0; d < 64; ++d) {
    float b0 = sb[wv][64 + d];
    float b1 = sb[wv][128 + d];
    o = fmaf(P0[d * 64 + lane], b0, o);
    o = fmaf(P1[d * 64 + lane], b1, o);
  }
  Eo[(size_t)p * DD + lane] = o;
}

// final pair scoring
__global__ void k_dot(const float* __restrict__ Eo, float* __restrict__ out) {
  int w = (blockIdx.x * blockDim.x + threadIdx.x) >> 6;
  int lane = threadIdx.x & 63;
  if (w >= BB) return;
  float pd = Eo[(size_t)w * DD + lane] * Eo[(size_t)(BB + w) * DD + lane];
#pragma unroll
  for (int o = 32; o; o >>= 1) pd += __shfl_xor(pd, o);
  if (lane == 0) out[w] = pd;
}

extern "C" void kernel_launch(void* const* d_in, const int* in_sizes, int n_in,
                              void* d_out, int out_size, void* d_ws, size_t ws_size,
                              hipStream_t stream) {
  const int* edge_src = (const int*)d_in[0];
  const int* edge_dst = (const int*)d_in[1];
  const float* edge_val = (const float*)d_in[2];
  const float* U_emb = (const float*)d_in[3];
  const float* V_emb = (const float*)d_in[4];
  const float* Wq = (const float*)d_in[5];
  const float* Wk = (const float*)d_in[6];
  const float* Wv = (const float*)d_in[7];
  const float* Wo = (const float*)d_in[8];
  const int* u = (const int*)d_in[9];
  const int* ii = (const int*)d_in[10];
  float* out = (float*)d_out;

  const float4* U4 = (const float4*)U_emb;
  const float4* V4 = (const float4*)V_emb;

  // workspace layout (16B-aligned base)
  float* Ea = (float*)d_ws;                          // NN*64  (E1; coarse scratch sv before)
  float* Eb = Ea + (size_t)NN * DD;                  // NN*64  (E2; coarse scratch dst before)
  float* Es = Eb + (size_t)NN * DD;                  // 4*NS*64
  float* Eo = Es + (size_t)4 * NS * DD;              // NS*64
  float* Mt = Eo + (size_t)NS * DD;                  // 2*4096
  float* Pm = Mt + 8192;                             // 2*4096
  int* row_ptr = (int*)(Pm + 8192);                  // NN+1
  int* need1 = row_ptr + NN + 1;                     // NN
  int* need2 = need1 + NN;                           // NN
  int* bcount = need2 + NN;                          // NB
  int* bbase = bcount + NB;                          // NB+1
  int* bcur = bbase + NB + 1;                        // NB
  uintptr_t pa = (uintptr_t)(bcur + NB);
  pa = (pa + 15) & ~(uintptr_t)15;
  int2* pairs = (int2*)pa;                           // NE int2

  int2* c_sv = (int2*)Ea;   // NE int2 (10.2MB) — dead before E1 write
  int* c_dst = (int*)Eb;    // NE int  (5.1MB)  — dead before E2 write

  float4* Ea4 = (float4*)Ea;
  float4* Eb4 = (float4*)Eb;
  float4* Es4 = (float4*)Es;

  // attention weight precompute (independent of graph work)
  k_prep<<<64, 256, 0, stream>>>(Wq, Wk, Wv, Wo, Mt, Pm);

  // CSR build: bucket hist -> bucket scan -> coarse bin -> fine place (+row_ptr)
  hipMemsetAsync(bcount, 0, NB * sizeof(int), stream);
  hipMemsetAsync(need1, 0, 2 * NN * sizeof(int), stream);
  int cgrid = (NE + CHUNK - 1) / CHUNK;
  k_bhist<<<cgrid, 256, 0, stream>>>(edge_dst, bcount);
  k_bscan<<<1, 1024, 0, stream>>>(bcount, bbase, bcur, row_ptr);
  k_coarse<<<cgrid, 256, 0, stream>>>(edge_src, edge_dst, edge_val, bcur, c_sv, c_dst);
  k_fine2<<<NB, 256, 0, stream>>>(bbase, c_sv, c_dst, pairs, row_ptr);

  // frontier marking
  k_mark_s<<<(NS + 255) / 256, 256, 0, stream>>>(u, ii, row_ptr, pairs, need1, need2);
  k_mark2<<<(NN + 255) / 256, 256, 0, stream>>>(row_ptr, pairs, need2, need1);

  int ggrid = (NS * 16 + 255) / 256;
  int pgrid = (NN * 64 + 255) / 256;

  k_gather<1><<<ggrid, 256, 0, stream>>>(U4, V4, nullptr, Es4 + (size_t)0 * NS * 16, u, ii);
  k_prop4<1><<<pgrid, 256, 0, stream>>>(U4, V4, nullptr, Ea4, row_ptr, pairs, need1);
  k_gather<0><<<ggrid, 256, 0, stream>>>(nullptr, nullptr, Ea4, Es4 + (size_t)1 * NS * 16, u, ii);
  k_prop4<0><<<pgrid, 256, 0, stream>>>(nullptr, nullptr, Ea4, Eb4, row_ptr, pairs, need2);
  k_gather<0><<<ggrid, 256, 0, stream>>>(nullptr, nullptr, Eb4, Es4 + (size_t)2 * NS * 16, u, ii);
  k_prop3<<<(NS * 64 + 255) / 256, 256, 0, stream>>>(Eb4, Es4 + (size_t)3 * NS * 16, row_ptr,
                                                     pairs, u, ii);

  k_attn2<<<(NS + 3) / 4, 256, 0, stream>>>(Es, Mt, Pm, Eo);
  k_dot<<<(BB * 64 + 255) / 256, 256, 0, stream>>>(Eo, out);
}